// Round 4
// baseline (10.588 us; speedup 1.0000x reference)
//
#include <hip/hip_runtime.h>

// Problem constants (from reference):
//   B=32, S=128, V=50257, C=16, F=8
// Inputs (d_in order): logits f32 [B,S,V], mlm_labels int [B,S],
//   labels int [B], weight f32 [C,F], m2c int [C,F], filler_len f32 [C]
// Output: 33 floats = [loss, predictions[0..31]]
//
// Structure: 512 threads = 8 waves; wave w owns rows b = 4w..4w+3 end-to-end
// (16 lanes per row, lane owns class c = lane&15). No LDS / no barrier until
// the single cross-wave loss reduction at the end.

#define PB 32
#define PS 128
#define PV 50257
#define PC 16
#define PF 8
#define NWAVE 8

__global__ __launch_bounds__(512) void pte_criterion_kernel(
    const float* __restrict__ logits,
    const int*   __restrict__ mlm_labels,
    const int*   __restrict__ labels,
    const float* __restrict__ weight,
    const int*   __restrict__ m2c,
    const float* __restrict__ filler_len,
    float*       __restrict__ out)
{
    __shared__ float wsum_s[NWAVE];

    const int tid  = threadIdx.x;
    const int lane = tid & 63;
    const int wv   = tid >> 6;
    const int g    = lane >> 4;      // 16-lane row-group within the wave
    const int c    = lane & 15;      // class index owned by this lane
    const int b    = tid >> 4;       // row index

    // ---- Issue ALL cold loads up front; every HBM miss overlaps ----
    const int4* ml4 = (const int4*)mlm_labels;
    const int4 v0 = ml4[tid * 2 + 0];
    const int4 v1 = ml4[tid * 2 + 1];
    const int4*   m2c4 = (const int4*)m2c;
    const int4    ma   = m2c4[c * 2 + 0];
    const int4    mb   = m2c4[c * 2 + 1];
    const float4* w4   = (const float4*)weight;
    const float4  wa   = w4[c * 2 + 0];
    const float4  wb   = w4[c * 2 + 1];
    const float   fl   = filler_len[c];
    const int     lab  = labels[b];

    // ---- pos[b]: first s with mlm >= 0, via ballot + shuffle (no LDS) ----
    const int s0 = (tid & 15) * 8;
    int local = PS;
    if (v1.w >= 0) local = s0 + 7;
    if (v1.z >= 0) local = s0 + 6;
    if (v1.y >= 0) local = s0 + 5;
    if (v1.x >= 0) local = s0 + 4;
    if (v0.w >= 0) local = s0 + 3;
    if (v0.z >= 0) local = s0 + 2;
    if (v0.y >= 0) local = s0 + 1;
    if (v0.x >= 0) local = s0 + 0;

    const unsigned long long m  = __ballot(local < PS);
    const unsigned long long gm = (m >> (g * 16)) & 0xFFFFull;
    const int srcLane = g * 16 + (gm ? (__ffsll(gm) - 1) : 0);
    const int pv  = __shfl(local, srcLane, 64);
    const int pos = gm ? pv : 0;     // jnp.argmax fallback when no True

    // ---- cls_logits[b][c]: 8 scattered gathers + FMA (one epoch) ----
    const float* mlrow = logits + ((size_t)b * PS + (size_t)pos) * (size_t)PV;
    float acc = 0.0f;
    if (ma.x > 0) acc += mlrow[ma.x] * wa.x;
    if (ma.y > 0) acc += mlrow[ma.y] * wa.y;
    if (ma.z > 0) acc += mlrow[ma.z] * wa.z;
    if (ma.w > 0) acc += mlrow[ma.w] * wa.w;
    if (mb.x > 0) acc += mlrow[mb.x] * wb.x;
    if (mb.y > 0) acc += mlrow[mb.y] * wb.y;
    if (mb.z > 0) acc += mlrow[mb.z] * wb.z;
    if (mb.w > 0) acc += mlrow[mb.w] * wb.w;
    const float cls = acc / fl;

    // ---- per-row argmax + logsumexp; label-logit folded into the butterfly ----
    float mx = cls;
    int   am = c;
    #pragma unroll
    for (int mask = 1; mask <= 8; mask <<= 1) {
        const float v2 = __shfl_xor(mx, mask, 64);
        const int   i2 = __shfl_xor(am, mask, 64);
        if (v2 > mx || (v2 == mx && i2 < am)) { mx = v2; am = i2; }  // first-max
    }
    float se   = __expf(cls - mx);
    float sel  = (c == lab) ? cls : 0.0f;   // exactly one lane per row matches
    #pragma unroll
    for (int mask = 1; mask <= 8; mask <<= 1) {
        se  += __shfl_xor(se,  mask, 64);
        sel += __shfl_xor(sel, mask, 64);
    }
    const float loss = (mx + __logf(se)) - sel;

    if (c == 0) out[1 + b] = (float)am;     // predictions

    // ---- wave partial: sum of this wave's 4 row losses ----
    float part = (c == 0) ? loss : 0.0f;    // 4 contributing lanes per wave
    #pragma unroll
    for (int mask = 16; mask <= 32; mask <<= 1) {
        part += __shfl_xor(part, mask, 64);
    }
    if (lane == 0) wsum_s[wv] = part;
    __syncthreads();

    // ---- final: 8 partials -> mean, by first 8 lanes of wave 0 ----
    if (tid < NWAVE) {
        float t = wsum_s[tid];
        #pragma unroll
        for (int mask = 1; mask <= 4; mask <<= 1) {
            t += __shfl_xor(t, mask, 64);
        }
        if (tid == 0) out[0] = t * (1.0f / (float)PB);
    }
}

extern "C" void kernel_launch(void* const* d_in, const int* in_sizes, int n_in,
                              void* d_out, int out_size, void* d_ws, size_t ws_size,
                              hipStream_t stream)
{
    const float* logits     = (const float*)d_in[0];
    const int*   mlm_labels = (const int*)  d_in[1];
    const int*   labels     = (const int*)  d_in[2];
    const float* weight     = (const float*)d_in[3];
    const int*   m2c        = (const int*)  d_in[4];
    const float* filler_len = (const float*)d_in[5];
    float*       out        = (float*)d_out;

    pte_criterion_kernel<<<1, 512, 0, stream>>>(
        logits, mlm_labels, labels, weight, m2c, filler_len, out);
}

// Round 5
// 9.650 us; speedup vs baseline: 1.0972x; 1.0972x over previous
//
#include <hip/hip_runtime.h>

// Problem constants (from reference):
//   B=32, S=128, V=50257, C=16, F=8
// Inputs (d_in order): logits f32 [B,S,V], mlm_labels int [B,S],
//   labels int [B], weight f32 [C,F], m2c int [C,F], filler_len f32 [C]
// Output: 33 floats = [loss, predictions[0..31]]
//
// Structure (best-measured, R3): 512 threads = 8 waves; wave w owns rows
// b = 4w..4w+3 end-to-end (16 lanes per row, lane owns class c = lane&15).
// One fused cold-load epoch, ballot/shfl pos-find, shfl-butterfly softmax,
// exactly one __syncthreads. Only change vs R3: __expf/__logf (HW
// v_exp_f32/v_log_f32) on the dependent tail.

#define PB 32
#define PS 128
#define PV 50257
#define PC 16
#define PF 8

__global__ __launch_bounds__(512) void pte_criterion_kernel(
    const float* __restrict__ logits,
    const int*   __restrict__ mlm_labels,
    const int*   __restrict__ labels,
    const float* __restrict__ weight,
    const int*   __restrict__ m2c,
    const float* __restrict__ filler_len,
    float*       __restrict__ out)
{
    __shared__ float loss_s[PB];

    const int tid  = threadIdx.x;
    const int lane = tid & 63;
    const int g    = lane >> 4;      // 16-lane row-group within the wave
    const int c    = lane & 15;      // class index owned by this lane
    const int b    = tid >> 4;       // row index

    // ---- Issue ALL cold loads up front; every HBM miss overlaps ----
    const int4* ml4 = (const int4*)mlm_labels;
    const int4 v0 = ml4[tid * 2 + 0];
    const int4 v1 = ml4[tid * 2 + 1];
    const int4*   m2c4 = (const int4*)m2c;
    const int4    ma   = m2c4[c * 2 + 0];
    const int4    mb   = m2c4[c * 2 + 1];
    const float4* w4   = (const float4*)weight;
    const float4  wa   = w4[c * 2 + 0];
    const float4  wb   = w4[c * 2 + 1];
    const float   fl   = filler_len[c];
    const int     lab  = labels[b];

    // ---- pos[b]: first s with mlm >= 0, via ballot + shuffle (no LDS) ----
    const int s0 = (tid & 15) * 8;
    int local = PS;
    if (v1.w >= 0) local = s0 + 7;
    if (v1.z >= 0) local = s0 + 6;
    if (v1.y >= 0) local = s0 + 5;
    if (v1.x >= 0) local = s0 + 4;
    if (v0.w >= 0) local = s0 + 3;
    if (v0.z >= 0) local = s0 + 2;
    if (v0.y >= 0) local = s0 + 1;
    if (v0.x >= 0) local = s0 + 0;

    const unsigned long long m  = __ballot(local < PS);
    const unsigned long long gm = (m >> (g * 16)) & 0xFFFFull;
    const int srcLane = g * 16 + (gm ? (__ffsll(gm) - 1) : 0);
    const int pv  = __shfl(local, srcLane, 64);
    const int pos = gm ? pv : 0;     // jnp.argmax fallback when no True

    // ---- cls_logits[b][c]: 8 scattered gathers + FMA (one epoch) ----
    const float* mlrow = logits + ((size_t)b * PS + (size_t)pos) * (size_t)PV;
    float acc = 0.0f;
    if (ma.x > 0) acc += mlrow[ma.x] * wa.x;
    if (ma.y > 0) acc += mlrow[ma.y] * wa.y;
    if (ma.z > 0) acc += mlrow[ma.z] * wa.z;
    if (ma.w > 0) acc += mlrow[ma.w] * wa.w;
    if (mb.x > 0) acc += mlrow[mb.x] * wb.x;
    if (mb.y > 0) acc += mlrow[mb.y] * wb.y;
    if (mb.z > 0) acc += mlrow[mb.z] * wb.z;
    if (mb.w > 0) acc += mlrow[mb.w] * wb.w;
    const float cls = acc / fl;

    // ---- per-row argmax + logsumexp via 16-lane shfl_xor butterflies ----
    float mx = cls;
    int   am = c;
    #pragma unroll
    for (int mask = 1; mask <= 8; mask <<= 1) {
        const float v2 = __shfl_xor(mx, mask, 64);
        const int   i2 = __shfl_xor(am, mask, 64);
        if (v2 > mx || (v2 == mx && i2 < am)) { mx = v2; am = i2; }  // first-max
    }
    float se = __expf(cls - mx);
    #pragma unroll
    for (int mask = 1; mask <= 8; mask <<= 1) {
        se += __shfl_xor(se, mask, 64);
    }
    const float clsl = __shfl(cls, g * 16 + lab, 64);
    const float loss = (mx + __logf(se)) - clsl;

    if (c == 0) {
        out[1 + b] = (float)am;      // prediction as float
        loss_s[b]  = loss;
    }
    __syncthreads();

    if (tid == 0) {
        float t = 0.0f;
        #pragma unroll
        for (int bb = 0; bb < PB; ++bb) t += loss_s[bb];
        out[0] = t / (float)PB;
    }
}

extern "C" void kernel_launch(void* const* d_in, const int* in_sizes, int n_in,
                              void* d_out, int out_size, void* d_ws, size_t ws_size,
                              hipStream_t stream)
{
    const float* logits     = (const float*)d_in[0];
    const int*   mlm_labels = (const int*)  d_in[1];
    const int*   labels     = (const int*)  d_in[2];
    const float* weight     = (const float*)d_in[3];
    const int*   m2c        = (const int*)  d_in[4];
    const float* filler_len = (const float*)d_in[5];
    float*       out        = (float*)d_out;

    pte_criterion_kernel<<<1, 512, 0, stream>>>(
        logits, mlm_labels, labels, weight, m2c, filler_len, out);
}